// Round 5
// baseline (4852.191 us; speedup 1.0000x reference)
//
#include <hip/hip_runtime.h>

#define BATCH    128
#define NPTS     32768
#define KOUT     1024
#define NTHREADS 1024
#define PPT      (NPTS / NTHREADS)   // 32 points per thread

// One block per batch. Coords pinned in AGPRs (gfx950 unified reg file):
// rounds 2-4 showed the allocator throttling to 64 arch VGPRs and
// REMATERIALIZING the 96 coord values from global every iteration
// (~300 KB/block/iter of L2 re-reads, VALUBusy 39%). asm-defined AGPR
// values cannot be rematerialized, so they stay resident. mindist moves
// from LDS into 32 VGPRs (loop-carried -> also not remat-able), removing
// all ds traffic from the inner loop.
__global__ __launch_bounds__(NTHREADS)
void fps_kernel(const float* __restrict__ x, float* __restrict__ out) {
    __shared__ float s_redv[16];
    __shared__ int   s_redi[16];
    __shared__ float s_pt[3];

    const int b   = blockIdx.x;
    const int tid = threadIdx.x;
    const float* __restrict__ xb = x + (size_t)b * 3 * NPTS;
    float* __restrict__ ob = out + (size_t)b * 3 * KOUT;

    // Load this thread's 32 points (n = tid + i*1024, coalesced) and pin
    // each coord into an AGPR.
    float xa[PPT], ya[PPT], za[PPT];
#pragma unroll
    for (int i = 0; i < PPT; ++i) {
        const int n = tid + i * NTHREADS;
        float vx = xb[n];
        float vy = xb[NPTS + n];
        float vz = xb[2 * NPTS + n];
        asm volatile("v_accvgpr_write_b32 %0, %1" : "=a"(xa[i]) : "v"(vx));
        asm volatile("v_accvgpr_write_b32 %0, %1" : "=a"(ya[i]) : "v"(vy));
        asm volatile("v_accvgpr_write_b32 %0, %1" : "=a"(za[i]) : "v"(vz));
    }

    // Per-thread mindist in registers.
    float md[PPT];
#pragma unroll
    for (int i = 0; i < PPT; ++i) md[i] = 1e10f;

    // First selected point is index 0.
    float px = xb[0], py = xb[NPTS], pz = xb[2 * NPTS];
    if (tid == 0) {
        ob[0] = px; ob[KOUT] = py; ob[2 * KOUT] = pz;
    }

    const int lane = tid & 63;
    const int wave = tid >> 6;

    for (int j = 1; j < KOUT; ++j) {
        float best = -1.0f;
        int   bi   = 0x7fffffff;

        // Distance update + running (first-occurrence) argmax.
        // Bit-exact vs reference (verified rounds 2-4, absmax 0):
        //   d = fma(dz,dz, fma(dy,dy, rn(dx*dx)))
#pragma unroll
        for (int i = 0; i < PPT; ++i) {
            float cx, cy, cz;
            asm volatile("v_accvgpr_read_b32 %0, %1" : "=v"(cx) : "a"(xa[i]));
            asm volatile("v_accvgpr_read_b32 %0, %1" : "=v"(cy) : "a"(ya[i]));
            asm volatile("v_accvgpr_read_b32 %0, %1" : "=v"(cz) : "a"(za[i]));
            const float dx = __fsub_rn(cx, px);
            const float dy = __fsub_rn(cy, py);
            const float dz = __fsub_rn(cz, pz);
            const float d  = __fmaf_rn(dz, dz,
                              __fmaf_rn(dy, dy,
                                __fmul_rn(dx, dx)));
            const float m  = fminf(md[i], d);
            md[i] = m;
            // indices increase with i, so strict > keeps the earliest
            // (lowest-index) occurrence of the max
            if (m > best) { best = m; bi = tid + i * NTHREADS; }
        }

        // Wave-level butterfly argmax (tie-break: smaller index wins).
#pragma unroll
        for (int s = 1; s < 64; s <<= 1) {
            const float ov = __shfl_xor(best, s, 64);
            const int   oi = __shfl_xor(bi,   s, 64);
            if (ov > best || (ov == best && oi < bi)) { best = ov; bi = oi; }
        }
        if (lane == 0) { s_redv[wave] = best; s_redi[wave] = bi; }
        __syncthreads();

        // Cross-wave reduce (16 partials) in wave 0; lane 0 fetches the
        // winner's coords from global (L3-resident) and publishes.
        if (wave == 0) {
            float v  = (lane < 16) ? s_redv[lane] : -1.0f;
            int   vi = (lane < 16) ? s_redi[lane] : 0x7fffffff;
#pragma unroll
            for (int s = 1; s < 16; s <<= 1) {
                const float ov = __shfl_xor(v,  s, 64);
                const int   oi = __shfl_xor(vi, s, 64);
                if (ov > v || (ov == v && oi < vi)) { v = ov; vi = oi; }
            }
            if (lane == 0) {
                const float sx = xb[vi];
                const float sy = xb[NPTS + vi];
                const float sz = xb[2 * NPTS + vi];
                s_pt[0] = sx; s_pt[1] = sy; s_pt[2] = sz;
                ob[j] = sx; ob[KOUT + j] = sy; ob[2 * KOUT + j] = sz;
            }
        }
        __syncthreads();
        px = s_pt[0]; py = s_pt[1]; pz = s_pt[2];
    }
}

extern "C" void kernel_launch(void* const* d_in, const int* in_sizes, int n_in,
                              void* d_out, int out_size, void* d_ws, size_t ws_size,
                              hipStream_t stream) {
    const float* x = (const float*)d_in[0];
    float* out = (float*)d_out;
    fps_kernel<<<BATCH, NTHREADS, 0, stream>>>(x, out);
}

// Round 6
// 4038.646 us; speedup vs baseline: 1.2014x; 1.2014x over previous
//
#include <hip/hip_runtime.h>

#define BATCH    128
#define NPTS     32768
#define KOUT     1024
#define NTHREADS 512
#define PPT      (NPTS / NTHREADS)   // 64 points per thread

// One block per batch, 512 threads = 8 waves = 2 waves/SIMD.
// mindist lives in STATIC 128 KiB LDS: compile-time-known LDS size makes
// the backend's occupancy calc see 1 block/CU -> 2 waves/SIMD -> a 256
// unified-VGPR budget, so the 192 coord registers stay resident instead of
// being rematerialized from global every iteration (rounds 2-4: dynamic
// LDS -> assumed occupancy 8 waves/SIMD -> 64-VGPR cap -> ~300 KB/blk/iter
// of L2/L3 re-reads, VALUBusy 39%).
__global__ __launch_bounds__(NTHREADS)
void fps_kernel(const float* __restrict__ x, float* __restrict__ out) {
    __shared__ float s_md[NPTS];      // 128 KiB, static
    __shared__ float s_redv[8];
    __shared__ int   s_redi[8];
    __shared__ float s_pt[3];

    const int b   = blockIdx.x;
    const int tid = threadIdx.x;
    const float* __restrict__ xb = x + (size_t)b * 3 * NPTS;
    float* __restrict__ ob = out + (size_t)b * 3 * KOUT;

    // Load this thread's 64 points (n = tid + i*512, lane-coalesced).
    float xs[PPT], ys[PPT], zs[PPT];
#pragma unroll
    for (int i = 0; i < PPT; ++i) {
        const int n = tid + i * NTHREADS;
        xs[i] = xb[n];
        ys[i] = xb[NPTS + n];
        zs[i] = xb[2 * NPTS + n];
        s_md[n] = 1e10f;
    }

    // First selected point is index 0.
    float px = xb[0], py = xb[NPTS], pz = xb[2 * NPTS];
    if (tid == 0) {
        ob[0] = px; ob[KOUT] = py; ob[2 * KOUT] = pz;
    }
    __syncthreads();

    const int lane = tid & 63;
    const int wave = tid >> 6;

    for (int j = 1; j < KOUT; ++j) {
        float best = -1.0f;
        int   bi   = 0x7fffffff;

        // Distance update + running (first-occurrence) argmax.
        // Bit-exact vs reference (verified rounds 2-4, absmax 0):
        //   d = fma(dz,dz, fma(dy,dy, rn(dx*dx)))
#pragma unroll
        for (int i = 0; i < PPT; ++i) {
            const int n = tid + i * NTHREADS;
            const float dx = __fsub_rn(xs[i], px);
            const float dy = __fsub_rn(ys[i], py);
            const float dz = __fsub_rn(zs[i], pz);
            const float d  = __fmaf_rn(dz, dz,
                              __fmaf_rn(dy, dy,
                                __fmul_rn(dx, dx)));
            const float m  = fminf(s_md[n], d);
            s_md[n] = m;
            // indices increase with i, so strict > keeps the earliest
            // (lowest-index) occurrence of the max
            if (m > best) { best = m; bi = n; }
        }

        // Wave-level butterfly argmax (tie-break: smaller index wins).
#pragma unroll
        for (int s = 1; s < 64; s <<= 1) {
            const float ov = __shfl_xor(best, s, 64);
            const int   oi = __shfl_xor(bi,   s, 64);
            if (ov > best || (ov == best && oi < bi)) { best = ov; bi = oi; }
        }
        if (lane == 0) { s_redv[wave] = best; s_redi[wave] = bi; }
        __syncthreads();

        // Cross-wave reduce (8 partials) in wave 0; lane 0 fetches the
        // winner's coords from global (L2/L3-resident) and publishes.
        if (wave == 0) {
            float v  = (lane < 8) ? s_redv[lane] : -1.0f;
            int   vi = (lane < 8) ? s_redi[lane] : 0x7fffffff;
#pragma unroll
            for (int s = 1; s < 8; s <<= 1) {
                const float ov = __shfl_xor(v,  s, 64);
                const int   oi = __shfl_xor(vi, s, 64);
                if (ov > v || (ov == v && oi < vi)) { v = ov; vi = oi; }
            }
            if (lane == 0) {
                const float sx = xb[vi];
                const float sy = xb[NPTS + vi];
                const float sz = xb[2 * NPTS + vi];
                s_pt[0] = sx; s_pt[1] = sy; s_pt[2] = sz;
                ob[j] = sx; ob[KOUT + j] = sy; ob[2 * KOUT + j] = sz;
            }
        }
        __syncthreads();
        px = s_pt[0]; py = s_pt[1]; pz = s_pt[2];
    }
}

extern "C" void kernel_launch(void* const* d_in, const int* in_sizes, int n_in,
                              void* d_out, int out_size, void* d_ws, size_t ws_size,
                              hipStream_t stream) {
    const float* x = (const float*)d_in[0];
    float* out = (float*)d_out;
    fps_kernel<<<BATCH, NTHREADS, 0, stream>>>(x, out);
}

// Round 7
// 4038.020 us; speedup vs baseline: 1.2016x; 1.0002x over previous
//
#include <hip/hip_runtime.h>

#define BATCH    128
#define NPTS     32768
#define KOUT     1024
#define NTHREADS 512
#define PPT      (NPTS / NTHREADS)   // 64 points per thread

// One block per batch, 512 threads = 8 waves = 2 waves/SIMD.
// 128 KiB static LDS already caps occupancy at 1 block/CU (2 waves/SIMD).
// amdgpu_waves_per_eu(2,2) tells the register allocator to budget for
// exactly that: 512-reg pool / 2 waves = 256 VGPRs/thread, enough for the
// 192 coord registers + temps. Round 6 (no attribute) showed the allocator
// defaults to a 4-waves/EU budget (VGPR_Count=128) and remats the
// overflow from global every iteration (FETCH 33.7 MB, VALUBusy 33%).
__global__ __launch_bounds__(NTHREADS)
__attribute__((amdgpu_waves_per_eu(2, 2)))
void fps_kernel(const float* __restrict__ x, float* __restrict__ out) {
    __shared__ float s_md[NPTS];      // 128 KiB, static
    __shared__ float s_redv[8];
    __shared__ int   s_redi[8];
    __shared__ float s_pt[3];

    const int b   = blockIdx.x;
    const int tid = threadIdx.x;
    const float* __restrict__ xb = x + (size_t)b * 3 * NPTS;
    float* __restrict__ ob = out + (size_t)b * 3 * KOUT;

    // Load this thread's 64 points (n = tid + i*512, lane-coalesced).
    float xs[PPT], ys[PPT], zs[PPT];
#pragma unroll
    for (int i = 0; i < PPT; ++i) {
        const int n = tid + i * NTHREADS;
        xs[i] = xb[n];
        ys[i] = xb[NPTS + n];
        zs[i] = xb[2 * NPTS + n];
        s_md[n] = 1e10f;
    }

    // First selected point is index 0.
    float px = xb[0], py = xb[NPTS], pz = xb[2 * NPTS];
    if (tid == 0) {
        ob[0] = px; ob[KOUT] = py; ob[2 * KOUT] = pz;
    }
    __syncthreads();

    const int lane = tid & 63;
    const int wave = tid >> 6;

    for (int j = 1; j < KOUT; ++j) {
        float best = -1.0f;
        int   bi   = 0x7fffffff;

        // Distance update + running (first-occurrence) argmax.
        // Bit-exact vs reference (verified rounds 2-6, absmax 0):
        //   d = fma(dz,dz, fma(dy,dy, rn(dx*dx)))
#pragma unroll
        for (int i = 0; i < PPT; ++i) {
            const int n = tid + i * NTHREADS;
            const float dx = __fsub_rn(xs[i], px);
            const float dy = __fsub_rn(ys[i], py);
            const float dz = __fsub_rn(zs[i], pz);
            const float d  = __fmaf_rn(dz, dz,
                              __fmaf_rn(dy, dy,
                                __fmul_rn(dx, dx)));
            const float m  = fminf(s_md[n], d);
            s_md[n] = m;
            // indices increase with i, so strict > keeps the earliest
            // (lowest-index) occurrence of the max
            if (m > best) { best = m; bi = n; }
        }

        // Wave-level butterfly argmax (tie-break: smaller index wins).
#pragma unroll
        for (int s = 1; s < 64; s <<= 1) {
            const float ov = __shfl_xor(best, s, 64);
            const int   oi = __shfl_xor(bi,   s, 64);
            if (ov > best || (ov == best && oi < bi)) { best = ov; bi = oi; }
        }
        if (lane == 0) { s_redv[wave] = best; s_redi[wave] = bi; }
        __syncthreads();

        // Cross-wave reduce (8 partials) in wave 0; lane 0 fetches the
        // winner's coords from global (L2/L3-resident) and publishes.
        if (wave == 0) {
            float v  = (lane < 8) ? s_redv[lane] : -1.0f;
            int   vi = (lane < 8) ? s_redi[lane] : 0x7fffffff;
#pragma unroll
            for (int s = 1; s < 8; s <<= 1) {
                const float ov = __shfl_xor(v,  s, 64);
                const int   oi = __shfl_xor(vi, s, 64);
                if (ov > v || (ov == v && oi < vi)) { v = ov; vi = oi; }
            }
            if (lane == 0) {
                const float sx = xb[vi];
                const float sy = xb[NPTS + vi];
                const float sz = xb[2 * NPTS + vi];
                s_pt[0] = sx; s_pt[1] = sy; s_pt[2] = sz;
                ob[j] = sx; ob[KOUT + j] = sy; ob[2 * KOUT + j] = sz;
            }
        }
        __syncthreads();
        px = s_pt[0]; py = s_pt[1]; pz = s_pt[2];
    }
}

extern "C" void kernel_launch(void* const* d_in, const int* in_sizes, int n_in,
                              void* d_out, int out_size, void* d_ws, size_t ws_size,
                              hipStream_t stream) {
    const float* x = (const float*)d_in[0];
    float* out = (float*)d_out;
    fps_kernel<<<BATCH, NTHREADS, 0, stream>>>(x, out);
}